// Round 15
// baseline (229.773 us; speedup 1.0000x reference)
//
#include <hip/hip_runtime.h>
#include <hip/hip_fp16.h>

#define Bc 4
#define Sc 2048
#define Dc 768
#define Hc 12
#define DKc 64

typedef _Float16 f16;
typedef __attribute__((ext_vector_type(8))) _Float16 f16x8;
typedef __attribute__((ext_vector_type(4))) _Float16 f16x4;
typedef __attribute__((ext_vector_type(4))) float f32x4;

static __device__ __forceinline__ f32x4 mfma16(f16x8 a, f16x8 b, f32x4 c) {
  return __builtin_amdgcn_mfma_f32_16x16x32_f16(a, b, c, 0, 0, 0);
}
static __device__ __forceinline__ f32x4 mfma16k16(f16x4 a, f16x4 b, f32x4 c) {
  return __builtin_amdgcn_mfma_f32_16x16x16f16(a, b, c, 0, 0, 0);
}

// async global->LDS, 16B per lane. LDS dest is wave-uniform base + lane*16.
#define GLD16(g, l)                                              \
  __builtin_amdgcn_global_load_lds(                              \
      (const __attribute__((address_space(1))) void*)(g),        \
      (__attribute__((address_space(3))) void*)(l), 16, 0, 0)

// T2 XOR swizzle: row stride 128B, byte col ^ ((row&7)<<4).  colB in [0,128).
#define SWZ(row, colB) (((row) << 7) + ((colB) ^ (((row) & 7) << 4)))

// ---------------- fused f32 -> f16 conversion (5 segments) ----------------
__global__ __launch_bounds__(256) void cvt5(
    const float* __restrict__ z, const float* __restrict__ w0,
    const float* __restrict__ w1, const float* __restrict__ w2,
    const float* __restrict__ w3, f16* __restrict__ oz, f16* __restrict__ o0,
    f16* __restrict__ o1, f16* __restrict__ o2, f16* __restrict__ o3) {
  const int bid = blockIdx.x;
  const float* in;
  f16* out;
  int i0;
  if (bid < 6144)      { in = z;  out = oz; i0 = bid * 256; }
  else if (bid < 6720) { in = w0; out = o0; i0 = (bid - 6144) * 256; }
  else if (bid < 7296) { in = w1; out = o1; i0 = (bid - 6720) * 256; }
  else if (bid < 7872) { in = w2; out = o2; i0 = (bid - 7296) * 256; }
  else                 { in = w3; out = o3; i0 = (bid - 7872) * 256; }
  const int i = i0 + threadIdx.x;
  float4 v = reinterpret_cast<const float4*>(in)[i];
  f16x4 o;
  o[0] = (f16)v.x; o[1] = (f16)v.y; o[2] = (f16)v.z; o[3] = (f16)v.w;
  reinterpret_cast<f16x4*>(out)[i] = o;
}

// ========= 128x256 BK=32 depth-2 counted-vmcnt pipelined GEMM ===============
// (R11-verified.) 8 waves (2M x 4N), per-wave 64x64 out, acc[4][4];
// 3 gloads/stage -> in-loop s_waitcnt vmcnt(3), never 0 until the last K-step.
// MODE 0: fused QKV projection, grid 576 (= 64 m x 9 n; n-tile picks weight).
// MODE 1: avg_weights, grid 512 (= 4 b x 16 m x 8 n), dst f32 * 1/96.
// MODE 2: fc, grid 192 (= 64 m x 3 n), A=Cx, B=W0, dst f32 + bias (bq).
template <int MODE>
__global__ __launch_bounds__(512, 2) void gemm128x256(
    const f16* __restrict__ A0, const f16* __restrict__ W0,
    const f16* __restrict__ W1, const f16* __restrict__ W2,
    const float* __restrict__ bq, const float* __restrict__ bk,
    const float* __restrict__ bv, f16* __restrict__ Qb, f16* __restrict__ Kb,
    f16* __restrict__ Vt, float* __restrict__ avg) {
  constexpr int K = Dc;           // 768
  constexpr int NK = K / 32;      // 24 K-steps
  const int tid = threadIdx.x;
  const int lane = tid & 63;
  const int w = tid >> 6;         // 0..7
  const int wr = w >> 2, wc = w & 3;
  const int l15 = lane & 15, lg = lane >> 4;

  const f16* Ab;
  const f16* Bb;
  long m0;
  int seg = 0, n0seg = 0, bat = 0, ncol0 = 0;
  if (MODE == 0) {
    const int wgid = (blockIdx.x & 7) * 72 + (blockIdx.x >> 3);  // 576 = 8*72
    const int mx = wgid / 9, nt = wgid % 9;
    m0 = (long)mx * 128;
    seg = nt / 3;
    n0seg = (nt % 3) * 256;
    const f16* Wsel = seg == 0 ? W0 : seg == 1 ? W1 : W2;
    Ab = A0 + m0 * K;
    Bb = Wsel + (long)n0seg * K;
  } else if (MODE == 1) {
    const int wgid = (blockIdx.x & 7) * 64 + (blockIdx.x >> 3);  // 512 = 8*64
    bat = wgid >> 7;
    const int t = wgid & 127;
    const int mx = t >> 3, nx = t & 7;
    m0 = (long)mx * 128;
    ncol0 = nx * 256;
    Ab = W0 + (long)bat * Sc * Dc + m0 * K;           // Q[b]
    Bb = W1 + (long)bat * Sc * Dc + (long)ncol0 * K;  // K[b]
  } else {
    const int wgid = (blockIdx.x & 7) * 24 + (blockIdx.x >> 3);  // 192 = 8*24
    const int mx = wgid / 3, nx = wgid % 3;
    m0 = (long)mx * 128;
    ncol0 = nx * 256;
    Ab = A0 + m0 * K;                                 // Cx
    Bb = W0 + (long)ncol0 * K;                        // fc weights
  }

  __shared__ f16 As[2][128 * 32];  // 16 KB
  __shared__ f16 Bs[2][256 * 32];  // 32 KB

  const int lr = lane >> 2;
  const int lc = (lane & 3) * 8;
  const f16* Ag0 = Ab + (long)(w * 16 + lr) * K + lc;
  const f16* Bg0 = Bb + (long)(w * 32 + lr) * K + lc;
  const f16* Bg1 = Bg0 + (long)16 * K;

#define STG(buf, k0)                            \
  {                                             \
    GLD16(Ag0 + (k0), &As[buf][w * 512]);       \
    GLD16(Bg0 + (k0), &Bs[buf][w * 1024]);      \
    GLD16(Bg1 + (k0), &Bs[buf][w * 1024 + 512]);\
  }

  f32x4 acc[4][4] = {};

  STG(0, 0)
  STG(1, 32)

#pragma unroll 1
  for (int i = 0; i < NK; ++i) {
    if (i + 1 < NK) {
      asm volatile("s_waitcnt vmcnt(3)" ::: "memory");
    } else {
      asm volatile("s_waitcnt vmcnt(0)" ::: "memory");
    }
    __builtin_amdgcn_sched_barrier(0);
    __builtin_amdgcn_s_barrier();
    __builtin_amdgcn_sched_barrier(0);

    const f16* Asb = &As[i & 1][0];
    const f16* Bsb = &Bs[i & 1][0];
    f16x8 af[4], bf[4];
#pragma unroll
    for (int mi = 0; mi < 4; ++mi)
      af[mi] = *reinterpret_cast<const f16x8*>(
          &Asb[(wr * 64 + mi * 16 + l15) * 32 + lg * 8]);
#pragma unroll
    for (int ni = 0; ni < 4; ++ni)
      bf[ni] = *reinterpret_cast<const f16x8*>(
          &Bsb[(wc * 64 + ni * 16 + l15) * 32 + lg * 8]);
#pragma unroll
    for (int mi = 0; mi < 4; ++mi)
#pragma unroll
      for (int ni = 0; ni < 4; ++ni)
        acc[mi][ni] = mfma16(af[mi], bf[ni], acc[mi][ni]);

    __builtin_amdgcn_sched_barrier(0);
    __builtin_amdgcn_s_barrier();
    __builtin_amdgcn_sched_barrier(0);
    if (i + 2 < NK) STG(i & 1, (i + 2) * 32)
  }
#undef STG

  if (MODE == 0) {
    const float* bias = seg == 0 ? bq : seg == 1 ? bk : bv;
    float bvv[4];
#pragma unroll
    for (int ni = 0; ni < 4; ++ni)
      bvv[ni] = bias[n0seg + wc * 64 + ni * 16 + l15];
    if (seg < 2) {
      f16* dq = seg == 0 ? Qb : Kb;
#pragma unroll
      for (int mi = 0; mi < 4; ++mi) {
#pragma unroll
        for (int ni = 0; ni < 4; ++ni) {
          const long col = n0seg + wc * 64 + ni * 16 + l15;
#pragma unroll
          for (int j = 0; j < 4; ++j) {
            const long row = m0 + wr * 64 + mi * 16 + lg * 4 + j;
            dq[row * Dc + col] = (f16)(acc[mi][ni][j] + bvv[ni]);
          }
        }
      }
    } else {
#pragma unroll
      for (int mi = 0; mi < 4; ++mi) {
#pragma unroll
        for (int ni = 0; ni < 4; ++ni) {
          const long col = n0seg + wc * 64 + ni * 16 + l15;
#pragma unroll
          for (int j = 0; j < 4; ++j) {
            const long row = m0 + wr * 64 + mi * 16 + lg * 4 + j;
            const long b = row >> 11, s = row & 2047;
            Vt[(b * Dc + col) * (long)Sc + s] = (f16)(acc[mi][ni][j] + bvv[ni]);
          }
        }
      }
    }
  } else if (MODE == 1) {
    float* dp = avg + (long)bat * Sc * Sc;
#pragma unroll
    for (int mi = 0; mi < 4; ++mi) {
#pragma unroll
      for (int ni = 0; ni < 4; ++ni) {
        const long col = ncol0 + wc * 64 + ni * 16 + l15;
#pragma unroll
        for (int j = 0; j < 4; ++j) {
          const long row = m0 + wr * 64 + mi * 16 + lg * 4 + j;
          dp[row * Sc + col] = acc[mi][ni][j] * (1.0f / 96.0f);
        }
      }
    }
  } else {
#pragma unroll
    for (int mi = 0; mi < 4; ++mi) {
#pragma unroll
      for (int ni = 0; ni < 4; ++ni) {
        const long col = ncol0 + wc * 64 + ni * 16 + l15;
        const float bv = bq[col];
#pragma unroll
        for (int j = 0; j < 4; ++j) {
          const long row = m0 + wr * 64 + mi * 16 + lg * 4 + j;
          avg[row * Dc + col] = acc[mi][ni][j] + bv;
        }
      }
    }
  }
}

// -------- flash attention: 8 waves/block, 128 q-rows, KVBLK=64, dbuf K/V ----
// Swapped QK^T, exp2 online softmax + defer-max, O^T = V^T@P^T via K=16 MFMA:
// the 16x16x16 B-operand layout (k = lg*4+0..3) EQUALS the QK D-output
// fragment layout, so P feeds PV straight from registers — no LDS round-trip,
// no Ps buffer (LDS 48->32 KB => 4 blocks/CU = wave cap).
__global__ __launch_bounds__(512) void attn8(const f16* __restrict__ Q,
                                             const f16* __restrict__ Km,
                                             const f16* __restrict__ Vt,
                                             f16* __restrict__ ctx) {
  const int tid = threadIdx.x;
  const int lane = tid & 63;
  const int w = tid >> 6;              // 0..7
  const int l15 = lane & 15, lg = lane >> 4;
  const int lid = (blockIdx.x & 7) * 96 + (blockIdx.x >> 3);
  const int qt = lid & 15;
  const int h  = (lid >> 4) % Hc;
  const int b  = lid / (16 * Hc);
  const int q0 = qt * 128 + w * 16;

  __shared__ f16 Ks[2][64 * 64];       // dbuf, 8 KB each
  __shared__ f16 Vs[2][64 * 64];       // dbuf, 8 KB each

  f16x8 qf[2];
  {
    const f16* qp = Q + ((long)(b * Sc + q0 + l15)) * Dc + h * DKc + lg * 8;
    qf[0] = *reinterpret_cast<const f16x8*>(qp);
    qf[1] = *reinterpret_cast<const f16x8*>(qp + 32);
  }

  const int srow = tid >> 3;           // 0..63
  const int scolB = (tid & 7) * 16;    // byte col 0..112
  const f16* Kg = Km + (long)(b * Sc) * Dc + h * DKc;
  const f16* Vg = Vt + ((long)(b * Dc + h * DKc)) * Sc;

  const float c2 = 0.18033688011f;     // log2(e) / temp, temp = 8
  float m2 = -1e30f, l_run = 0.f;
  f32x4 o[4] = {};

  // prologue: stage tile 0 into buf 0 (swizzled)
  *reinterpret_cast<f16x8*>((char*)Ks[0] + SWZ(srow, scolB)) =
      *reinterpret_cast<const f16x8*>(Kg + (long)srow * Dc + scolB / 2);
  *reinterpret_cast<f16x8*>((char*)Vs[0] + SWZ(srow, scolB)) =
      *reinterpret_cast<const f16x8*>(Vg + (long)srow * Sc + scolB / 2);
  __syncthreads();

#pragma unroll 1
  for (int i = 0; i < Sc / 64; ++i) {
    const int kv0 = i * 64;
    const bool pf = (i + 1) < Sc / 64;
    char* kb = (char*)Ks[i & 1];
    char* vb = (char*)Vs[i & 1];
    f16x8 kr, vr;
    if (pf) {  // T14: issue next-tile loads now; ds_write after PV (to buf^1)
      kr = *reinterpret_cast<const f16x8*>(Kg + (long)(kv0 + 64 + srow) * Dc + scolB / 2);
      vr = *reinterpret_cast<const f16x8*>(Vg + (long)srow * Sc + kv0 + 64 + scolB / 2);
    }

    // swapped QK^T: sc[t] -> D[kv][q], lane: q = l15, kv = t*16 + lg*4 + j
    f32x4 sc[4];
    __builtin_amdgcn_s_setprio(1);
#pragma unroll
    for (int t = 0; t < 4; ++t) {
      const int row = t * 16 + l15;
      f32x4 s = {};
      s = mfma16(*reinterpret_cast<const f16x8*>(kb + SWZ(row, lg * 16)), qf[0], s);
      s = mfma16(*reinterpret_cast<const f16x8*>(kb + SWZ(row, 64 + lg * 16)), qf[1], s);
      sc[t] = s;
    }
    __builtin_amdgcn_s_setprio(0);

    // online softmax, log2 domain, defer-max (THR = 8 nats = 11.544 bits)
    float mx = sc[0][0];
#pragma unroll
    for (int t = 0; t < 4; ++t)
#pragma unroll
      for (int j = 0; j < 4; ++j) mx = fmaxf(mx, sc[t][j]);
    const float mx2 = mx * c2;
    float al = 1.0f;
    if (!__all(mx2 <= m2 + 11.544f)) {
      float g = fmaxf(mx2, __shfl_xor(mx2, 16));
      g = fmaxf(g, __shfl_xor(g, 32));
      const float mn2 = fmaxf(m2, g);
      al = __builtin_amdgcn_exp2f(m2 - mn2);
      m2 = mn2;
#pragma unroll
      for (int c = 0; c < 4; ++c)
#pragma unroll
        for (int j = 0; j < 4; ++j) o[c][j] *= al;
    }
    float ps = 0.f;
    f16x4 pp[4];
#pragma unroll
    for (int t = 0; t < 4; ++t)
#pragma unroll
      for (int j = 0; j < 4; ++j) {
        float p = __builtin_amdgcn_exp2f(__builtin_fmaf(sc[t][j], c2, -m2));
        pp[t][j] = (f16)p;
        ps += p;
      }
    ps += __shfl_xor(ps, 16);
    ps += __shfl_xor(ps, 32);
    l_run = l_run * al + ps;

    // PV via K=16 MFMA: B = pp[t] DIRECT from registers (layout match).
    // A = V^T[dk=c*16+l15][kv=t*16+lg*4..+3] = 8B swizzled LDS read.
    __builtin_amdgcn_s_setprio(1);
#pragma unroll
    for (int c = 0; c < 4; ++c) {
      const int row = c * 16 + l15;
      f32x4 oc = o[c];
#pragma unroll
      for (int t = 0; t < 4; ++t) {
        f16x4 va = *reinterpret_cast<const f16x4*>(vb + SWZ(row, t * 32 + lg * 8));
        oc = mfma16k16(va, pp[t], oc);
      }
      o[c] = oc;
    }
    __builtin_amdgcn_s_setprio(0);

    if (pf) {
      // stage into the OTHER buffer; one barrier makes it visible and orders
      // next tile's writes after this tile's reads.
      *reinterpret_cast<f16x8*>((char*)Ks[(i + 1) & 1] + SWZ(srow, scolB)) = kr;
      *reinterpret_cast<f16x8*>((char*)Vs[(i + 1) & 1] + SWZ(srow, scolB)) = vr;
      __syncthreads();
    }
  }

  // epilogue: o[c][j] = O^T[dk = c*16 + lg*4 + j][q = l15]
  const float inv = 1.0f / l_run;
  f16* cp = ctx + ((long)(b * Sc) + q0 + l15) * Dc + h * DKc;
#pragma unroll
  for (int c = 0; c < 4; ++c) {
    f16x4 ov;
#pragma unroll
    for (int j = 0; j < 4; ++j) ov[j] = (f16)(o[c][j] * inv);
    *reinterpret_cast<f16x4*>(cp + c * 16 + lg * 4) = ov;
  }
}

extern "C" void kernel_launch(void* const* d_in, const int* in_sizes, int n_in,
                              void* d_out, int out_size, void* d_ws, size_t ws_size,
                              hipStream_t stream) {
  (void)in_sizes; (void)n_in; (void)out_size; (void)ws_size;
  const float* z    = (const float*)d_in[0];
  const float* wq_w = (const float*)d_in[1];
  const float* wq_b = (const float*)d_in[2];
  const float* wk_w = (const float*)d_in[3];
  const float* wk_b = (const float*)d_in[4];
  const float* wv_w = (const float*)d_in[5];
  const float* wv_b = (const float*)d_in[6];
  const float* fc_w = (const float*)d_in[7];
  const float* fc_b = (const float*)d_in[8];
  float* out = (float*)d_out;

  char* ws = (char*)d_ws;
  size_t off = 0;
  auto alloc = [&](size_t bytes) -> void* {
    void* p = (void*)(ws + off);
    off += (bytes + 255) & ~(size_t)255;
    return p;
  };
  const size_t zdb = (size_t)Bc * Sc * Dc * sizeof(f16);   // 12.6 MB
  const size_t wdb = (size_t)Dc * Dc * sizeof(f16);        // 1.2 MB
  f16* zb  = (f16*)alloc(zdb);
  f16* wqb = (f16*)alloc(wdb);
  f16* wkb = (f16*)alloc(wdb);
  f16* wvb = (f16*)alloc(wdb);
  f16* fcb = (f16*)alloc(wdb);
  f16* Qb  = (f16*)alloc(zdb);
  f16* Kb  = (f16*)alloc(zdb);
  f16* Vt  = (f16*)alloc(zdb);
  f16* Cx  = zb;  // alias: zb is dead after the QKV projection

  cvt5<<<8448, 256, 0, stream>>>(z, wq_w, wk_w, wv_w, fc_w, zb, wqb, wkb, wvb, fcb);

  // fused QKV projection: 576 blocks (128x256 tiles, deep pipeline)
  gemm128x256<0><<<576, 512, 0, stream>>>(zb, wqb, wkb, wvb, wq_b, wk_b, wv_b,
                                          Qb, Kb, Vt, nullptr);

  // avg_weights = (Qfull @ Kfull^T) / 96: 512 blocks
  gemm128x256<1><<<512, 512, 0, stream>>>(nullptr, Qb, Kb, nullptr, nullptr,
                                          nullptr, nullptr, nullptr, nullptr,
                                          nullptr, out + (size_t)Bc * Sc * Dc);

  attn8<<<Bc * Hc * (Sc / 128), 512, 0, stream>>>(Qb, Kb, Vt, Cx);

  // fc: 192 blocks (128x256 tiles, deep pipeline, MODE 2)
  gemm128x256<2><<<192, 512, 0, stream>>>(Cx, fcb, nullptr, nullptr, fc_b,
                                          nullptr, nullptr, nullptr, nullptr,
                                          nullptr, out);
}

// Round 16
// 203.154 us; speedup vs baseline: 1.1310x; 1.1310x over previous
//
#include <hip/hip_runtime.h>
#include <hip/hip_fp16.h>

#define Bc 4
#define Sc 2048
#define Dc 768
#define Hc 12
#define DKc 64

typedef _Float16 f16;
typedef __attribute__((ext_vector_type(8))) _Float16 f16x8;
typedef __attribute__((ext_vector_type(4))) _Float16 f16x4;
typedef __attribute__((ext_vector_type(2))) _Float16 f16x2;
typedef __attribute__((ext_vector_type(2))) __fp16 h2raw;
typedef __attribute__((ext_vector_type(4))) float f32x4;

static __device__ __forceinline__ f32x4 mfma16(f16x8 a, f16x8 b, f32x4 c) {
  return __builtin_amdgcn_mfma_f32_16x16x32_f16(a, b, c, 0, 0, 0);
}
static __device__ __forceinline__ float fdot2f(h2raw a, h2raw b, float c) {
  return __builtin_amdgcn_fdot2(a, b, c, false);
}
#define M3(a, b, c) fmaxf(fmaxf((a), (b)), (c))

// async global->LDS, 16B per lane. LDS dest is wave-uniform base + lane*16.
#define GLD16(g, l)                                              \
  __builtin_amdgcn_global_load_lds(                              \
      (const __attribute__((address_space(1))) void*)(g),        \
      (__attribute__((address_space(3))) void*)(l), 16, 0, 0)

// T2 XOR swizzle: row stride 128B, byte col ^ ((row&7)<<4).  colB in [0,128).
#define SWZ(row, colB) (((row) << 7) + ((colB) ^ (((row) & 7) << 4)))

// ---------------- fused f32 -> f16 conversion (5 segments) ----------------
__global__ __launch_bounds__(256) void cvt5(
    const float* __restrict__ z, const float* __restrict__ w0,
    const float* __restrict__ w1, const float* __restrict__ w2,
    const float* __restrict__ w3, f16* __restrict__ oz, f16* __restrict__ o0,
    f16* __restrict__ o1, f16* __restrict__ o2, f16* __restrict__ o3) {
  const int bid = blockIdx.x;
  const float* in;
  f16* out;
  int i0;
  if (bid < 6144)      { in = z;  out = oz; i0 = bid * 256; }
  else if (bid < 6720) { in = w0; out = o0; i0 = (bid - 6144) * 256; }
  else if (bid < 7296) { in = w1; out = o1; i0 = (bid - 6720) * 256; }
  else if (bid < 7872) { in = w2; out = o2; i0 = (bid - 7296) * 256; }
  else                 { in = w3; out = o3; i0 = (bid - 7872) * 256; }
  const int i = i0 + threadIdx.x;
  float4 v = reinterpret_cast<const float4*>(in)[i];
  f16x4 o;
  o[0] = (f16)v.x; o[1] = (f16)v.y; o[2] = (f16)v.z; o[3] = (f16)v.w;
  reinterpret_cast<f16x4*>(out)[i] = o;
}

// ========= 128x256 BK=32 depth-2 counted-vmcnt pipelined GEMM ===============
// (R11-verified.) 8 waves (2M x 4N), per-wave 64x64 out, acc[4][4];
// 3 gloads/stage -> in-loop s_waitcnt vmcnt(3), never 0 until the last K-step.
// MODE 0: fused QKV projection, grid 576 (= 64 m x 9 n; n-tile picks weight).
// MODE 1: avg_weights, grid 512 (= 4 b x 16 m x 8 n), dst f32 * 1/96.
// MODE 2: fc, grid 192 (= 64 m x 3 n), A=Cx, B=W0, dst f32 + bias (bq).
template <int MODE>
__global__ __launch_bounds__(512, 2) void gemm128x256(
    const f16* __restrict__ A0, const f16* __restrict__ W0,
    const f16* __restrict__ W1, const f16* __restrict__ W2,
    const float* __restrict__ bq, const float* __restrict__ bk,
    const float* __restrict__ bv, f16* __restrict__ Qb, f16* __restrict__ Kb,
    f16* __restrict__ Vt, float* __restrict__ avg) {
  constexpr int K = Dc;           // 768
  constexpr int NK = K / 32;      // 24 K-steps
  const int tid = threadIdx.x;
  const int lane = tid & 63;
  const int w = tid >> 6;         // 0..7
  const int wr = w >> 2, wc = w & 3;
  const int l15 = lane & 15, lg = lane >> 4;

  const f16* Ab;
  const f16* Bb;
  long m0;
  int seg = 0, n0seg = 0, bat = 0, ncol0 = 0;
  if (MODE == 0) {
    const int wgid = (blockIdx.x & 7) * 72 + (blockIdx.x >> 3);  // 576 = 8*72
    const int mx = wgid / 9, nt = wgid % 9;
    m0 = (long)mx * 128;
    seg = nt / 3;
    n0seg = (nt % 3) * 256;
    const f16* Wsel = seg == 0 ? W0 : seg == 1 ? W1 : W2;
    Ab = A0 + m0 * K;
    Bb = Wsel + (long)n0seg * K;
  } else if (MODE == 1) {
    const int wgid = (blockIdx.x & 7) * 64 + (blockIdx.x >> 3);  // 512 = 8*64
    bat = wgid >> 7;
    const int t = wgid & 127;
    const int mx = t >> 3, nx = t & 7;
    m0 = (long)mx * 128;
    ncol0 = nx * 256;
    Ab = W0 + (long)bat * Sc * Dc + m0 * K;           // Q[b]
    Bb = W1 + (long)bat * Sc * Dc + (long)ncol0 * K;  // K[b]
  } else {
    const int wgid = (blockIdx.x & 7) * 24 + (blockIdx.x >> 3);  // 192 = 8*24
    const int mx = wgid / 3, nx = wgid % 3;
    m0 = (long)mx * 128;
    ncol0 = nx * 256;
    Ab = A0 + m0 * K;                                 // Cx
    Bb = W0 + (long)ncol0 * K;                        // fc weights
  }

  __shared__ f16 As[2][128 * 32];  // 16 KB
  __shared__ f16 Bs[2][256 * 32];  // 32 KB

  const int lr = lane >> 2;
  const int lc = (lane & 3) * 8;
  const f16* Ag0 = Ab + (long)(w * 16 + lr) * K + lc;
  const f16* Bg0 = Bb + (long)(w * 32 + lr) * K + lc;
  const f16* Bg1 = Bg0 + (long)16 * K;

#define STG(buf, k0)                            \
  {                                             \
    GLD16(Ag0 + (k0), &As[buf][w * 512]);       \
    GLD16(Bg0 + (k0), &Bs[buf][w * 1024]);      \
    GLD16(Bg1 + (k0), &Bs[buf][w * 1024 + 512]);\
  }

  f32x4 acc[4][4] = {};

  STG(0, 0)
  STG(1, 32)

#pragma unroll 1
  for (int i = 0; i < NK; ++i) {
    if (i + 1 < NK) {
      asm volatile("s_waitcnt vmcnt(3)" ::: "memory");
    } else {
      asm volatile("s_waitcnt vmcnt(0)" ::: "memory");
    }
    __builtin_amdgcn_sched_barrier(0);
    __builtin_amdgcn_s_barrier();
    __builtin_amdgcn_sched_barrier(0);

    const f16* Asb = &As[i & 1][0];
    const f16* Bsb = &Bs[i & 1][0];
    f16x8 af[4], bf[4];
#pragma unroll
    for (int mi = 0; mi < 4; ++mi)
      af[mi] = *reinterpret_cast<const f16x8*>(
          &Asb[(wr * 64 + mi * 16 + l15) * 32 + lg * 8]);
#pragma unroll
    for (int ni = 0; ni < 4; ++ni)
      bf[ni] = *reinterpret_cast<const f16x8*>(
          &Bsb[(wc * 64 + ni * 16 + l15) * 32 + lg * 8]);
#pragma unroll
    for (int mi = 0; mi < 4; ++mi)
#pragma unroll
      for (int ni = 0; ni < 4; ++ni)
        acc[mi][ni] = mfma16(af[mi], bf[ni], acc[mi][ni]);

    __builtin_amdgcn_sched_barrier(0);
    __builtin_amdgcn_s_barrier();
    __builtin_amdgcn_sched_barrier(0);
    if (i + 2 < NK) STG(i & 1, (i + 2) * 32)
  }
#undef STG

  if (MODE == 0) {
    const float* bias = seg == 0 ? bq : seg == 1 ? bk : bv;
    float bvv[4];
#pragma unroll
    for (int ni = 0; ni < 4; ++ni)
      bvv[ni] = bias[n0seg + wc * 64 + ni * 16 + l15];
    if (seg < 2) {
      f16* dq = seg == 0 ? Qb : Kb;
#pragma unroll
      for (int mi = 0; mi < 4; ++mi) {
#pragma unroll
        for (int ni = 0; ni < 4; ++ni) {
          const long col = n0seg + wc * 64 + ni * 16 + l15;
#pragma unroll
          for (int j = 0; j < 4; ++j) {
            const long row = m0 + wr * 64 + mi * 16 + lg * 4 + j;
            dq[row * Dc + col] = (f16)(acc[mi][ni][j] + bvv[ni]);
          }
        }
      }
    } else {
#pragma unroll
      for (int mi = 0; mi < 4; ++mi) {
#pragma unroll
        for (int ni = 0; ni < 4; ++ni) {
          const long col = n0seg + wc * 64 + ni * 16 + l15;
#pragma unroll
          for (int j = 0; j < 4; ++j) {
            const long row = m0 + wr * 64 + mi * 16 + lg * 4 + j;
            const long b = row >> 11, s = row & 2047;
            Vt[(b * Dc + col) * (long)Sc + s] = (f16)(acc[mi][ni][j] + bvv[ni]);
          }
        }
      }
    }
  } else if (MODE == 1) {
    float* dp = avg + (long)bat * Sc * Sc;
#pragma unroll
    for (int mi = 0; mi < 4; ++mi) {
#pragma unroll
      for (int ni = 0; ni < 4; ++ni) {
        const long col = ncol0 + wc * 64 + ni * 16 + l15;
#pragma unroll
        for (int j = 0; j < 4; ++j) {
          const long row = m0 + wr * 64 + mi * 16 + lg * 4 + j;
          dp[row * Sc + col] = acc[mi][ni][j] * (1.0f / 96.0f);
        }
      }
    }
  } else {
#pragma unroll
    for (int mi = 0; mi < 4; ++mi) {
#pragma unroll
      for (int ni = 0; ni < 4; ++ni) {
        const long col = ncol0 + wc * 64 + ni * 16 + l15;
        const float bv = bq[col];
#pragma unroll
        for (int j = 0; j < 4; ++j) {
          const long row = m0 + wr * 64 + mi * 16 + lg * 4 + j;
          avg[row * Dc + col] = acc[mi][ni][j] + bv;
        }
      }
    }
  }
}

// -------- flash attention: 8 waves/block, 128 q-rows, KVBLK=64, dbuf K/V ----
// R8-verified structure (83.5 us). This round: softmax instruction-count cuts
// only — v_max3 tree (15 fmax -> 8), cvt_pkrtz (16 cvt -> 8), v_dot2 row-sum
// (16 add -> 8). l now sums the exact f16 P values PV consumes.
__global__ __launch_bounds__(512) void attn8(const f16* __restrict__ Q,
                                             const f16* __restrict__ Km,
                                             const f16* __restrict__ Vt,
                                             f16* __restrict__ ctx) {
  const int tid = threadIdx.x;
  const int lane = tid & 63;
  const int w = tid >> 6;              // 0..7
  const int l15 = lane & 15, lg = lane >> 4;
  const int lid = (blockIdx.x & 7) * 96 + (blockIdx.x >> 3);
  const int qt = lid & 15;
  const int h  = (lid >> 4) % Hc;
  const int b  = lid / (16 * Hc);
  const int q0 = qt * 128 + w * 16;

  __shared__ f16 Ks[2][64 * 64];       // dbuf, 8 KB each
  __shared__ f16 Vs[2][64 * 64];       // dbuf, 8 KB each
  __shared__ f16 Ps[8 * 16 * 64];      // per-wave 2 KB
  char* pb = (char*)Ps + (w << 11);

  f16x8 qf[2];
  {
    const f16* qp = Q + ((long)(b * Sc + q0 + l15)) * Dc + h * DKc + lg * 8;
    qf[0] = *reinterpret_cast<const f16x8*>(qp);
    qf[1] = *reinterpret_cast<const f16x8*>(qp + 32);
  }
  h2raw one2;
  one2[0] = (__fp16)1.0f; one2[1] = (__fp16)1.0f;

  const int srow = tid >> 3;           // 0..63
  const int scolB = (tid & 7) * 16;    // byte col 0..112
  const f16* Kg = Km + (long)(b * Sc) * Dc + h * DKc;
  const f16* Vg = Vt + ((long)(b * Dc + h * DKc)) * Sc;

  const float c2 = 0.18033688011f;     // log2(e) / temp, temp = 8
  float m2 = -1e30f, l_run = 0.f;
  f32x4 o[4] = {};

  // prologue: stage tile 0 into buf 0 (swizzled)
  *reinterpret_cast<f16x8*>((char*)Ks[0] + SWZ(srow, scolB)) =
      *reinterpret_cast<const f16x8*>(Kg + (long)srow * Dc + scolB / 2);
  *reinterpret_cast<f16x8*>((char*)Vs[0] + SWZ(srow, scolB)) =
      *reinterpret_cast<const f16x8*>(Vg + (long)srow * Sc + scolB / 2);
  __syncthreads();

#pragma unroll 1
  for (int i = 0; i < Sc / 64; ++i) {
    const int kv0 = i * 64;
    const bool pf = (i + 1) < Sc / 64;
    char* kb = (char*)Ks[i & 1];
    char* vb = (char*)Vs[i & 1];
    f16x8 kr, vr;
    if (pf) {  // T14: issue next-tile loads now; ds_write after PV (to buf^1)
      kr = *reinterpret_cast<const f16x8*>(Kg + (long)(kv0 + 64 + srow) * Dc + scolB / 2);
      vr = *reinterpret_cast<const f16x8*>(Vg + (long)srow * Sc + kv0 + 64 + scolB / 2);
    }

    // swapped QK^T: sc[t] -> D[kv][q], lane: q = l15, kv = t*16 + lg*4 + j
    f32x4 sc[4];
    __builtin_amdgcn_s_setprio(1);
#pragma unroll
    for (int t = 0; t < 4; ++t) {
      const int row = t * 16 + l15;
      f32x4 s = {};
      s = mfma16(*reinterpret_cast<const f16x8*>(kb + SWZ(row, lg * 16)), qf[0], s);
      s = mfma16(*reinterpret_cast<const f16x8*>(kb + SWZ(row, 64 + lg * 16)), qf[1], s);
      sc[t] = s;
    }
    __builtin_amdgcn_s_setprio(0);

    // online softmax, log2 domain, defer-max (THR = 8 nats = 11.544 bits)
    // max over 16 via v_max3 tree (8 ops)
    const float t0 = M3(sc[0][0], sc[0][1], sc[0][2]);
    const float t1 = M3(sc[0][3], sc[1][0], sc[1][1]);
    const float t2 = M3(sc[1][2], sc[1][3], sc[2][0]);
    const float t3 = M3(sc[2][1], sc[2][2], sc[2][3]);
    const float t4 = M3(sc[3][0], sc[3][1], sc[3][2]);
    float mx = M3(t0, t1, t2);
    mx = M3(mx, t3, t4);
    mx = fmaxf(mx, sc[3][3]);
    const float mx2 = mx * c2;
    float al = 1.0f;
    if (!__all(mx2 <= m2 + 11.544f)) {
      float g = fmaxf(mx2, __shfl_xor(mx2, 16));
      g = fmaxf(g, __shfl_xor(g, 32));
      const float mn2 = fmaxf(m2, g);
      al = __builtin_amdgcn_exp2f(m2 - mn2);
      m2 = mn2;
#pragma unroll
      for (int c = 0; c < 4; ++c)
#pragma unroll
        for (int j = 0; j < 4; ++j) o[c][j] *= al;
    }
    float ps = 0.f;
    f16x4 pp[4];
#pragma unroll
    for (int t = 0; t < 4; ++t) {
      const float p0 = __builtin_amdgcn_exp2f(__builtin_fmaf(sc[t][0], c2, -m2));
      const float p1 = __builtin_amdgcn_exp2f(__builtin_fmaf(sc[t][1], c2, -m2));
      const float p2 = __builtin_amdgcn_exp2f(__builtin_fmaf(sc[t][2], c2, -m2));
      const float p3 = __builtin_amdgcn_exp2f(__builtin_fmaf(sc[t][3], c2, -m2));
      const h2raw lo = __builtin_amdgcn_cvt_pkrtz(p0, p1);
      const h2raw hi = __builtin_amdgcn_cvt_pkrtz(p2, p3);
      const f16x2 lo2 = __builtin_bit_cast(f16x2, lo);
      const f16x2 hi2 = __builtin_bit_cast(f16x2, hi);
      pp[t][0] = lo2[0]; pp[t][1] = lo2[1]; pp[t][2] = hi2[0]; pp[t][3] = hi2[1];
      ps = fdot2f(lo, one2, ps);
      ps = fdot2f(hi, one2, ps);
    }
    ps += __shfl_xor(ps, 16);
    ps += __shfl_xor(ps, 32);
    l_run = l_run * al + ps;

    // P^T regs -> Ps (per-wave, swizzled): row q=l15, byte col = t*32 + lg*8
#pragma unroll
    for (int t = 0; t < 4; ++t)
      *reinterpret_cast<f16x4*>(pb + SWZ(l15, t * 32 + lg * 8)) = pp[t];
    asm volatile("s_waitcnt lgkmcnt(0)" ::: "memory");
    __builtin_amdgcn_sched_barrier(0);

    // PV: O^T += V^T @ P^T
    f16x8 pa0 = *reinterpret_cast<const f16x8*>(pb + SWZ(l15, lg * 16));
    f16x8 pa1 = *reinterpret_cast<const f16x8*>(pb + SWZ(l15, 64 + lg * 16));
    __builtin_amdgcn_s_setprio(1);
#pragma unroll
    for (int c = 0; c < 4; ++c) {
      const int row = c * 16 + l15;
      o[c] = mfma16(*reinterpret_cast<const f16x8*>(vb + SWZ(row, lg * 16)), pa0, o[c]);
      o[c] = mfma16(*reinterpret_cast<const f16x8*>(vb + SWZ(row, 64 + lg * 16)), pa1, o[c]);
    }
    __builtin_amdgcn_s_setprio(0);

    if (pf) {
      // stage into the OTHER buffer; one barrier makes it visible and orders
      // next tile's writes after this tile's reads.
      *reinterpret_cast<f16x8*>((char*)Ks[(i + 1) & 1] + SWZ(srow, scolB)) = kr;
      *reinterpret_cast<f16x8*>((char*)Vs[(i + 1) & 1] + SWZ(srow, scolB)) = vr;
      __syncthreads();
    }
  }

  // epilogue: o[c][j] = O^T[dk = c*16 + lg*4 + j][q = l15]
  const float inv = 1.0f / l_run;
  f16* cp = ctx + ((long)(b * Sc) + q0 + l15) * Dc + h * DKc;
#pragma unroll
  for (int c = 0; c < 4; ++c) {
    f16x4 ov;
#pragma unroll
    for (int j = 0; j < 4; ++j) ov[j] = (f16)(o[c][j] * inv);
    *reinterpret_cast<f16x4*>(cp + c * 16 + lg * 4) = ov;
  }
}

extern "C" void kernel_launch(void* const* d_in, const int* in_sizes, int n_in,
                              void* d_out, int out_size, void* d_ws, size_t ws_size,
                              hipStream_t stream) {
  (void)in_sizes; (void)n_in; (void)out_size; (void)ws_size;
  const float* z    = (const float*)d_in[0];
  const float* wq_w = (const float*)d_in[1];
  const float* wq_b = (const float*)d_in[2];
  const float* wk_w = (const float*)d_in[3];
  const float* wk_b = (const float*)d_in[4];
  const float* wv_w = (const float*)d_in[5];
  const float* wv_b = (const float*)d_in[6];
  const float* fc_w = (const float*)d_in[7];
  const float* fc_b = (const float*)d_in[8];
  float* out = (float*)d_out;

  char* ws = (char*)d_ws;
  size_t off = 0;
  auto alloc = [&](size_t bytes) -> void* {
    void* p = (void*)(ws + off);
    off += (bytes + 255) & ~(size_t)255;
    return p;
  };
  const size_t zdb = (size_t)Bc * Sc * Dc * sizeof(f16);   // 12.6 MB
  const size_t wdb = (size_t)Dc * Dc * sizeof(f16);        // 1.2 MB
  f16* zb  = (f16*)alloc(zdb);
  f16* wqb = (f16*)alloc(wdb);
  f16* wkb = (f16*)alloc(wdb);
  f16* wvb = (f16*)alloc(wdb);
  f16* fcb = (f16*)alloc(wdb);
  f16* Qb  = (f16*)alloc(zdb);
  f16* Kb  = (f16*)alloc(zdb);
  f16* Vt  = (f16*)alloc(zdb);
  f16* Cx  = zb;  // alias: zb is dead after the QKV projection

  cvt5<<<8448, 256, 0, stream>>>(z, wq_w, wk_w, wv_w, fc_w, zb, wqb, wkb, wvb, fcb);

  // fused QKV projection: 576 blocks (128x256 tiles, deep pipeline)
  gemm128x256<0><<<576, 512, 0, stream>>>(zb, wqb, wkb, wvb, wq_b, wk_b, wv_b,
                                          Qb, Kb, Vt, nullptr);

  // avg_weights = (Qfull @ Kfull^T) / 96: 512 blocks
  gemm128x256<1><<<512, 512, 0, stream>>>(nullptr, Qb, Kb, nullptr, nullptr,
                                          nullptr, nullptr, nullptr, nullptr,
                                          nullptr, out + (size_t)Bc * Sc * Dc);

  attn8<<<Bc * Hc * (Sc / 128), 512, 0, stream>>>(Qb, Kb, Vt, Cx);

  // fc: 192 blocks (128x256 tiles, deep pipeline, MODE 2)
  gemm128x256<2><<<192, 512, 0, stream>>>(Cx, fcb, nullptr, nullptr, fc_b,
                                          nullptr, nullptr, nullptr, nullptr,
                                          nullptr, out);
}